// Round 2
// baseline (599.740 us; speedup 1.0000x reference)
//
#include <hip/hip_runtime.h>

typedef __bf16 v8bf __attribute__((ext_vector_type(8)));
typedef float f32x4 __attribute__((ext_vector_type(4)));

#define DEVI static __device__ __forceinline__

DEVI v8bf load8(const __bf16* p) { return *reinterpret_cast<const v8bf*>(p); }

DEVI f32x4 mfma16(v8bf a, v8bf b, f32x4 c) {
  return __builtin_amdgcn_mfma_f32_16x16x32_bf16(a, b, c, 0, 0, 0);
}

DEVI v8bf zero8() {
  v8bf z;
#pragma unroll
  for (int t = 0; t < 8; ++t) z[t] = (__bf16)0.0f;
  return z;
}

#define SCALE_Q 0.08838834764831845f  // 128^-0.5

// ------------------------------------------------------------------
// f32 -> bf16 cast (weights, rel tables)
// ------------------------------------------------------------------
__global__ void k_cast(const float* __restrict__ src, __bf16* __restrict__ dst, int n) {
  int i = blockIdx.x * 256 + threadIdx.x;
  if (i < n) dst[i] = (__bf16)src[i];
}

// ------------------------------------------------------------------
// Repack conv weights: Wt[tap][o][c] = wfc[o][c][kh][kw], tap = kh*3+kw
// ------------------------------------------------------------------
__global__ void k_repack(const float* __restrict__ wfc, __bf16* __restrict__ Wt) {
  int idx = blockIdx.x * 256 + threadIdx.x;      // 9*512*512 total
  int c = idx & 511, o = (idx >> 9) & 511, tap = idx >> 18;
  Wt[idx] = (__bf16)wfc[((size_t)o * 512 + c) * 9 + tap];
}

// ------------------------------------------------------------------
// BN1 + ReLU on fp32 x, transpose (b,c,s) -> (b,s,c), bf16 out
// ------------------------------------------------------------------
__global__ void k_bn1(const float* __restrict__ x, const float* __restrict__ g,
                      const float* __restrict__ bb, const float* __restrict__ m,
                      const float* __restrict__ v, __bf16* __restrict__ y) {
  __shared__ float tile[32][33];
  const int b = blockIdx.z, c0 = blockIdx.y * 32, s0 = blockIdx.x * 32;
  const int tx = threadIdx.x, ty = threadIdx.y;   // 32 x 8
#pragma unroll
  for (int r = 0; r < 4; ++r) {
    int c = c0 + ty + r * 8;
    float inv = g[c] * rsqrtf(v[c] + 1e-5f);
    float beta = bb[c] - m[c] * inv;
    float val = x[((size_t)b * 512 + c) * 1024 + s0 + tx] * inv + beta;
    tile[ty + r * 8][tx] = fmaxf(val, 0.0f);
  }
  __syncthreads();
#pragma unroll
  for (int r = 0; r < 4; ++r) {
    int s = s0 + ty + r * 8;
    y[((size_t)b * 1024 + s) * 512 + c0 + tx] = (__bf16)tile[tx][ty + r * 8];
  }
}

// ------------------------------------------------------------------
// BN2 + ReLU on fp32 x2, transpose (b,c,s) -> (b,s,c), bf16 out
// ------------------------------------------------------------------
__global__ void k_bn2(const float* __restrict__ x2, const float* __restrict__ g,
                      const float* __restrict__ bb, const float* __restrict__ m,
                      const float* __restrict__ v, __bf16* __restrict__ z) {
  __shared__ float tile[32][33];
  const int b = blockIdx.z, c0 = blockIdx.y * 32, s0 = blockIdx.x * 32;
  const int tx = threadIdx.x, ty = threadIdx.y;
#pragma unroll
  for (int r = 0; r < 4; ++r) {
    int c = c0 + ty + r * 8;
    float inv = g[c] * rsqrtf(v[c] + 1e-5f);
    float beta = bb[c] - m[c] * inv;
    float val = x2[((size_t)b * 512 + c) * 1024 + s0 + tx] * inv + beta;
    tile[ty + r * 8][tx] = fmaxf(val, 0.0f);
  }
  __syncthreads();
#pragma unroll
  for (int r = 0; r < 4; ++r) {
    int s = s0 + ty + r * 8;
    z[((size_t)b * 1024 + s) * 512 + c0 + tx] = (__bf16)tile[tx][ty + r * 8];
  }
}

// ------------------------------------------------------------------
// QKV projection. A = [w_qk; w_v] bf16 (1536 x 512, k contiguous),
// B = y (b, s, c) with c contiguous. Wave computes 32x32 (2x2 MFMA tiles).
// q scaled by SCALE_Q, stored (b,n,s,d); k stored (b,n,s,d); v stored (b,n,d,s).
// ------------------------------------------------------------------
__global__ __launch_bounds__(256) void k_proj(
    const __bf16* __restrict__ wqk, const __bf16* __restrict__ wv,
    const __bf16* __restrict__ y, __bf16* __restrict__ qout,
    __bf16* __restrict__ kout, __bf16* __restrict__ vout) {
  const int b = blockIdx.z;
  const int wave = threadIdx.x >> 6, lane = threadIdx.x & 63;
  const int l15 = lane & 15, quad = lane >> 4;
  const int obase = blockIdx.x * 64 + (wave >> 1) * 32;
  const int sbase = blockIdx.y * 64 + (wave & 1) * 32;
  const __bf16* Amat = (obase < 1024) ? (wqk + (size_t)obase * 512)
                                      : (wv + (size_t)(obase - 1024) * 512);
  const __bf16* Bbase = y + (size_t)b * 1024 * 512;

  const f32x4 fz = {0.f, 0.f, 0.f, 0.f};
  f32x4 acc[2][2];
#pragma unroll
  for (int io = 0; io < 2; ++io)
#pragma unroll
    for (int jo = 0; jo < 2; ++jo) acc[io][jo] = fz;

  for (int k0 = 0; k0 < 512; k0 += 32) {
    v8bf a0 = load8(Amat + (size_t)l15 * 512 + k0 + quad * 8);
    v8bf a1 = load8(Amat + (size_t)(16 + l15) * 512 + k0 + quad * 8);
    v8bf b0 = load8(Bbase + (size_t)(sbase + l15) * 512 + k0 + quad * 8);
    v8bf b1 = load8(Bbase + (size_t)(sbase + 16 + l15) * 512 + k0 + quad * 8);
    acc[0][0] = mfma16(a0, b0, acc[0][0]);
    acc[0][1] = mfma16(a0, b1, acc[0][1]);
    acc[1][0] = mfma16(a1, b0, acc[1][0]);
    acc[1][1] = mfma16(a1, b1, acc[1][1]);
  }

#pragma unroll
  for (int io = 0; io < 2; ++io)
#pragma unroll
    for (int jo = 0; jo < 2; ++jo)
#pragma unroll
      for (int r = 0; r < 4; ++r) {
        int o = obase + io * 16 + quad * 4 + r;   // C row = quad*4+reg
        int s = sbase + jo * 16 + l15;            // C col = lane&15
        float val = acc[io][jo][r];
        if (o < 512) {
          int n = o >> 7, d = o & 127;
          qout[(((size_t)b * 4 + n) * 1024 + s) * 128 + d] = (__bf16)(val * SCALE_Q);
        } else if (o < 1024) {
          int oe = o - 512; int n = oe >> 7, d = oe & 127;
          kout[(((size_t)b * 4 + n) * 1024 + s) * 128 + d] = (__bf16)val;
        } else {
          int oe = o - 1024; int n = oe >> 7, d = oe & 127;
          vout[(((size_t)b * 4 + n) * 128 + d) * 1024 + s] = (__bf16)val;
        }
      }
}

// ------------------------------------------------------------------
// Attention: one block = (b, head, 16-row q tile). Logit stripes live in
// registers (wave w owns cols [w*256, w*256+256)); rel-bias tables via MFMA;
// cross-wave softmax via LDS partials; un-normalized P -> LDS bf16 -> PV.
// Epilogue: x2 = attn/den + x   (fp32).
// ------------------------------------------------------------------
__global__ __launch_bounds__(256) void k_attn(
    const __bf16* __restrict__ q, const __bf16* __restrict__ kmat,
    const __bf16* __restrict__ vt, const __bf16* __restrict__ relh,
    const __bf16* __restrict__ relw, const float* __restrict__ x,
    float* __restrict__ x2) {
  __shared__ __bf16 qld[16][136];   // +8 pad
  __shared__ float rw[16][64];
  __shared__ float rh[16][64];
  __shared__ float pmax[4][16];
  __shared__ float psum[4][16];
  __shared__ __bf16 pld[16][1032];  // +8 pad

  const int s0 = blockIdx.x * 16;
  const int n = blockIdx.y, b = blockIdx.z;
  const int tid = threadIdx.x;
  const int wave = tid >> 6, lane = tid & 63;
  const int l15 = lane & 15, quad = lane >> 4;
  const size_t hoff = ((size_t)(b * 4 + n)) << 17;  // *1024*128

  {  // q tile -> LDS (one 16B load per thread)
    int flat = tid * 8, i = flat >> 7, d = flat & 127;
    *reinterpret_cast<v8bf*>(&qld[i][d]) = load8(q + hoff + (size_t)(s0 + i) * 128 + d);
  }
  __syncthreads();

  v8bf afrag[4];  // A operand: q rows, m = lane&15, k = quad*8+j
#pragma unroll
  for (int kk = 0; kk < 4; ++kk)
    afrag[kk] = *reinterpret_cast<const v8bf*>(&qld[l15][kk * 32 + quad * 8]);

  // --- rel bias tables: RW[i][rr] = q_i . rel_w[rr],  RH likewise ---
#pragma unroll
  for (int tb = 0; tb < 2; ++tb) {
    const __bf16* rel = tb ? relh : relw;
    float* dst = tb ? &rh[0][0] : &rw[0][0];
    int rr = wave * 16 + l15;
    bool ok = rr < 63;
    const __bf16* bp = rel + (size_t)(ok ? rr : 62) * 128;
    f32x4 acc = {0.f, 0.f, 0.f, 0.f};
#pragma unroll
    for (int kk = 0; kk < 4; ++kk) {
      v8bf bf = load8(bp + kk * 32 + quad * 8);
      if (!ok) bf = zero8();
      acc = mfma16(afrag[kk], bf, acc);
    }
#pragma unroll
    for (int r = 0; r < 4; ++r) dst[(quad * 4 + r) * 64 + wave * 16 + l15] = acc[r];
  }

  // --- logits stripe in registers ---
  f32x4 sc[16];
#pragma unroll
  for (int jt = 0; jt < 16; ++jt) {
    int jb = wave * 256 + jt * 16;
    const __bf16* bp = kmat + hoff + (size_t)(jb + l15) * 128;
    f32x4 acc = {0.f, 0.f, 0.f, 0.f};
#pragma unroll
    for (int kk = 0; kk < 4; ++kk)
      acc = mfma16(afrag[kk], load8(bp + kk * 32 + quad * 8), acc);
    sc[jt] = acc;
  }
  __syncthreads();  // rw/rh visible to all waves

  // --- add rel bias, per-row max partials ---
  float rmax[4] = {-1e30f, -1e30f, -1e30f, -1e30f};
#pragma unroll
  for (int jt = 0; jt < 16; ++jt) {
    int j = wave * 256 + jt * 16 + l15;
    int hj = j >> 5, wj = j & 31;
#pragma unroll
    for (int r = 0; r < 4; ++r) {
      int i = quad * 4 + r;
      int si = s0 + i;
      float val = sc[jt][r] + rw[i][wj - (si & 31) + 31] + rh[i][hj - (si >> 5) + 31];
      sc[jt][r] = val;
      rmax[r] = fmaxf(rmax[r], val);
    }
  }
#pragma unroll
  for (int r = 0; r < 4; ++r)
#pragma unroll
    for (int msk = 8; msk >= 1; msk >>= 1)
      rmax[r] = fmaxf(rmax[r], __shfl_xor(rmax[r], msk));
  if (l15 == 0) {
#pragma unroll
    for (int r = 0; r < 4; ++r) pmax[wave][quad * 4 + r] = rmax[r];
  }
  __syncthreads();

  // --- exp, partial sums, write un-normalized P (bf16) ---
  float M[4], rsum[4] = {0.f, 0.f, 0.f, 0.f};
#pragma unroll
  for (int r = 0; r < 4; ++r) {
    int i = quad * 4 + r;
    M[r] = fmaxf(fmaxf(pmax[0][i], pmax[1][i]), fmaxf(pmax[2][i], pmax[3][i]));
  }
#pragma unroll
  for (int jt = 0; jt < 16; ++jt) {
    int j = wave * 256 + jt * 16 + l15;
#pragma unroll
    for (int r = 0; r < 4; ++r) {
      float p = __expf(sc[jt][r] - M[r]);
      rsum[r] += p;
      pld[quad * 4 + r][j] = (__bf16)p;
    }
  }
#pragma unroll
  for (int r = 0; r < 4; ++r)
#pragma unroll
    for (int msk = 8; msk >= 1; msk >>= 1)
      rsum[r] += __shfl_xor(rsum[r], msk);
  if (l15 == 0) {
#pragma unroll
    for (int r = 0; r < 4; ++r) psum[wave][quad * 4 + r] = rsum[r];
  }
  __syncthreads();

  // --- PV: out[i][d] = sum_j P[i][j] * V[j][d]; V stored (d, s) ---
  const f32x4 fz = {0.f, 0.f, 0.f, 0.f};
  f32x4 o0 = fz, o1 = fz;
  const int d0 = wave * 16, d1 = wave * 16 + 64;
  const __bf16* vb0 = vt + hoff + (size_t)(d0 + l15) * 1024;
  const __bf16* vb1 = vt + hoff + (size_t)(d1 + l15) * 1024;
  for (int j0 = 0; j0 < 1024; j0 += 32) {
    v8bf pa = *reinterpret_cast<const v8bf*>(&pld[l15][j0 + quad * 8]);
    o0 = mfma16(pa, load8(vb0 + j0 + quad * 8), o0);
    o1 = mfma16(pa, load8(vb1 + j0 + quad * 8), o1);
  }
#pragma unroll
  for (int r = 0; r < 4; ++r) {
    int i = quad * 4 + r;
    float inv = 1.0f / (psum[0][i] + psum[1][i] + psum[2][i] + psum[3][i]);
    int s = s0 + i;
    size_t i0 = ((size_t)b * 512 + n * 128 + d0 + l15) * 1024 + s;
    size_t i1 = ((size_t)b * 512 + n * 128 + d1 + l15) * 1024 + s;
    x2[i0] = o0[r] * inv + x[i0];
    x2[i1] = o1[r] * inv + x[i1];
  }
}

// ------------------------------------------------------------------
// 3x3 conv as 9-tap implicit GEMM. A = Wt[tap] (o,c), B = z (b,s,c).
// Wave computes 32x32 (2x2 MFMA tiles). out = conv + bias + x2 (fp32 out).
// ------------------------------------------------------------------
__global__ __launch_bounds__(256) void k_conv(
    const __bf16* __restrict__ Wt, const __bf16* __restrict__ z,
    const float* __restrict__ bias, const float* __restrict__ x2,
    float* __restrict__ out) {
  const int b = blockIdx.z;
  const int wave = threadIdx.x >> 6, lane = threadIdx.x & 63;
  const int l15 = lane & 15, quad = lane >> 4;
  const int obase = blockIdx.x * 64 + (wave >> 1) * 32;
  const int sbase = blockIdx.y * 64 + (wave & 1) * 32;
  const __bf16* zb = z + (size_t)b * 1024 * 512;

  const f32x4 fz = {0.f, 0.f, 0.f, 0.f};
  f32x4 acc[2][2];
#pragma unroll
  for (int io = 0; io < 2; ++io)
#pragma unroll
    for (int jo = 0; jo < 2; ++jo) acc[io][jo] = fz;

  for (int tap = 0; tap < 9; ++tap) {
    int dh = tap / 3 - 1, dw = tap % 3 - 1;
    const __bf16* A0 = Wt + ((size_t)tap * 512 + obase) * 512;
    int soff[2]; bool ok[2];
#pragma unroll
    for (int jo = 0; jo < 2; ++jo) {
      int s = sbase + jo * 16 + l15;
      int hh = (s >> 5) + dh, ww = (s & 31) + dw;
      ok[jo] = ((unsigned)hh < 32u) && ((unsigned)ww < 32u);
      soff[jo] = ok[jo] ? (hh * 32 + ww) * 512 : 0;
    }
    for (int k0 = 0; k0 < 512; k0 += 32) {
      v8bf a0 = load8(A0 + (size_t)l15 * 512 + k0 + quad * 8);
      v8bf a1 = load8(A0 + (size_t)(16 + l15) * 512 + k0 + quad * 8);
      v8bf b0 = load8(zb + soff[0] + k0 + quad * 8);
      v8bf b1 = load8(zb + soff[1] + k0 + quad * 8);
      if (!ok[0]) b0 = zero8();
      if (!ok[1]) b1 = zero8();
      acc[0][0] = mfma16(a0, b0, acc[0][0]);
      acc[0][1] = mfma16(a0, b1, acc[0][1]);
      acc[1][0] = mfma16(a1, b0, acc[1][0]);
      acc[1][1] = mfma16(a1, b1, acc[1][1]);
    }
  }

#pragma unroll
  for (int io = 0; io < 2; ++io)
#pragma unroll
    for (int jo = 0; jo < 2; ++jo)
#pragma unroll
      for (int r = 0; r < 4; ++r) {
        int o = obase + io * 16 + quad * 4 + r;
        int s = sbase + jo * 16 + l15;
        size_t idx = ((size_t)b * 512 + o) * 1024 + s;
        out[idx] = acc[io][jo][r] + bias[o] + x2[idx];
      }
}

// ------------------------------------------------------------------
extern "C" void kernel_launch(void* const* d_in, const int* in_sizes, int n_in,
                              void* d_out, int out_size, void* d_ws, size_t ws_size,
                              hipStream_t stream) {
  const float* x    = (const float*)d_in[0];
  const float* wqk  = (const float*)d_in[1];
  const float* wv   = (const float*)d_in[2];
  const float* relh = (const float*)d_in[3];
  const float* relw = (const float*)d_in[4];
  const float* g1   = (const float*)d_in[5];
  const float* b1   = (const float*)d_in[6];
  const float* m1   = (const float*)d_in[7];
  const float* v1   = (const float*)d_in[8];
  const float* g2   = (const float*)d_in[9];
  const float* b2   = (const float*)d_in[10];
  const float* m2   = (const float*)d_in[11];
  const float* v2   = (const float*)d_in[12];
  const float* wfc  = (const float*)d_in[13];
  const float* bfc  = (const float*)d_in[14];
  float* out = (float*)d_out;

  char* p = (char*)d_ws;
  __bf16* y   = (__bf16*)p; p += (size_t)8 * 1024 * 512 * 2;       // (b,s,c); reused as z
  __bf16* qb  = (__bf16*)p; p += (size_t)8 * 4 * 1024 * 128 * 2;   // (b,n,s,d)
  __bf16* kb  = (__bf16*)p; p += (size_t)8 * 4 * 1024 * 128 * 2;   // (b,n,s,d)
  __bf16* vb  = (__bf16*)p; p += (size_t)8 * 4 * 1024 * 128 * 2;   // (b,n,d,s)
  __bf16* Wt  = (__bf16*)p; p += (size_t)9 * 512 * 512 * 2;        // (tap,o,c)
  __bf16* wqkb = (__bf16*)p; p += (size_t)1024 * 512 * 2;
  __bf16* wvb  = (__bf16*)p; p += (size_t)512 * 512 * 2;
  __bf16* rhb  = (__bf16*)p; p += 32768;
  __bf16* rwb  = (__bf16*)p; p += 32768;
  float*  x2  = (float*)p;  p += (size_t)8 * 512 * 1024 * 4;       // (b,c,s) fp32

  k_cast<<<dim3((1024 * 512 + 255) / 256), dim3(256), 0, stream>>>(wqk, wqkb, 1024 * 512);
  k_cast<<<dim3((512 * 512 + 255) / 256), dim3(256), 0, stream>>>(wv, wvb, 512 * 512);
  k_cast<<<dim3((63 * 128 + 255) / 256), dim3(256), 0, stream>>>(relh, rhb, 63 * 128);
  k_cast<<<dim3((63 * 128 + 255) / 256), dim3(256), 0, stream>>>(relw, rwb, 63 * 128);
  k_repack<<<dim3(9 * 512 * 512 / 256), dim3(256), 0, stream>>>(wfc, Wt);
  k_bn1<<<dim3(32, 16, 8), dim3(32, 8), 0, stream>>>(x, g1, b1, m1, v1, y);
  k_proj<<<dim3(24, 16, 8), dim3(256), 0, stream>>>(wqkb, wvb, y, qb, kb, vb);
  k_attn<<<dim3(64, 4, 8), dim3(256), 0, stream>>>(qb, kb, vb, rhb, rwb, x, x2);
  k_bn2<<<dim3(32, 16, 8), dim3(32, 8), 0, stream>>>(x2, g2, b2, m2, v2, y);
  k_conv<<<dim3(8, 16, 8), dim3(256), 0, stream>>>(Wt, y, bfc, x2, out);
}

// Round 3
// 435.259 us; speedup vs baseline: 1.3779x; 1.3779x over previous
//
#include <hip/hip_runtime.h>

typedef __bf16 v8bf __attribute__((ext_vector_type(8)));
typedef float f32x4 __attribute__((ext_vector_type(4)));

#define DEVI static __device__ __forceinline__

DEVI v8bf load8(const __bf16* p) { return *reinterpret_cast<const v8bf*>(p); }

DEVI f32x4 mfma16(v8bf a, v8bf b, f32x4 c) {
  return __builtin_amdgcn_mfma_f32_16x16x32_bf16(a, b, c, 0, 0, 0);
}

DEVI v8bf zero8() {
  v8bf z;
#pragma unroll
  for (int t = 0; t < 8; ++t) z[t] = (__bf16)0.0f;
  return z;
}

// async global -> LDS, 16 bytes per lane. LDS dest: wave-uniform base + lane*16.
DEVI void gld16(const __bf16* g, __bf16* l) {
  __builtin_amdgcn_global_load_lds(
      (const __attribute__((address_space(1))) unsigned int*)(const void*)g,
      (__attribute__((address_space(3))) unsigned int*)(void*)l, 16, 0, 0);
}

#define SCALE_Q 0.08838834764831845f  // 128^-0.5

// ------------------------------------------------------------------
__global__ void k_cast(const float* __restrict__ src, __bf16* __restrict__ dst, int n) {
  int i = blockIdx.x * 256 + threadIdx.x;
  if (i < n) dst[i] = (__bf16)src[i];
}

// zero the padded-z buffer (16B per thread)
__global__ void k_zero(float* __restrict__ p) {
  int i = blockIdx.x * 256 + threadIdx.x;
  f32x4 z = {0.f, 0.f, 0.f, 0.f};
  reinterpret_cast<f32x4*>(p)[i] = z;
}

// ------------------------------------------------------------------
// Repack conv weights: Wt[tap][o][c] = wfc[o][c][kh][kw], tap = kh*3+kw
// ------------------------------------------------------------------
__global__ void k_repack(const float* __restrict__ wfc, __bf16* __restrict__ Wt) {
  int idx = blockIdx.x * 256 + threadIdx.x;      // 9*512*512 total
  int c = idx & 511, o = (idx >> 9) & 511, tap = idx >> 18;
  Wt[idx] = (__bf16)wfc[((size_t)o * 512 + c) * 9 + tap];
}

// ------------------------------------------------------------------
// BN1 + ReLU on fp32 x, transpose (b,c,s) -> (b,s,c), bf16 out
// ------------------------------------------------------------------
__global__ void k_bn1(const float* __restrict__ x, const float* __restrict__ g,
                      const float* __restrict__ bb, const float* __restrict__ m,
                      const float* __restrict__ v, __bf16* __restrict__ y) {
  __shared__ float tile[32][33];
  const int b = blockIdx.z, c0 = blockIdx.y * 32, s0 = blockIdx.x * 32;
  const int tx = threadIdx.x, ty = threadIdx.y;   // 32 x 8
#pragma unroll
  for (int r = 0; r < 4; ++r) {
    int c = c0 + ty + r * 8;
    float inv = g[c] * rsqrtf(v[c] + 1e-5f);
    float beta = bb[c] - m[c] * inv;
    float val = x[((size_t)b * 512 + c) * 1024 + s0 + tx] * inv + beta;
    tile[ty + r * 8][tx] = fmaxf(val, 0.0f);
  }
  __syncthreads();
#pragma unroll
  for (int r = 0; r < 4; ++r) {
    int s = s0 + ty + r * 8;
    y[((size_t)b * 1024 + s) * 512 + c0 + tx] = (__bf16)tile[tx][ty + r * 8];
  }
}

// ------------------------------------------------------------------
// BN2 + ReLU on fp32 x2, transpose (b,c,s) -> padded (b,34,34,c), bf16 out
// ------------------------------------------------------------------
__global__ void k_bn2(const float* __restrict__ x2, const float* __restrict__ g,
                      const float* __restrict__ bb, const float* __restrict__ m,
                      const float* __restrict__ v, __bf16* __restrict__ zp) {
  __shared__ float tile[32][33];
  const int b = blockIdx.z, c0 = blockIdx.y * 32, s0 = blockIdx.x * 32;
  const int tx = threadIdx.x, ty = threadIdx.y;
#pragma unroll
  for (int r = 0; r < 4; ++r) {
    int c = c0 + ty + r * 8;
    float inv = g[c] * rsqrtf(v[c] + 1e-5f);
    float beta = bb[c] - m[c] * inv;
    float val = x2[((size_t)b * 512 + c) * 1024 + s0 + tx] * inv + beta;
    tile[ty + r * 8][tx] = fmaxf(val, 0.0f);
  }
  __syncthreads();
#pragma unroll
  for (int r = 0; r < 4; ++r) {
    int s = s0 + ty + r * 8;
    int hh = s >> 5, ww = s & 31;
    zp[(((size_t)b * 34 + hh + 1) * 34 + ww + 1) * 512 + c0 + tx] =
        (__bf16)tile[tx][ty + r * 8];
  }
}

// ------------------------------------------------------------------
// QKV projection (unchanged).
// ------------------------------------------------------------------
__global__ __launch_bounds__(256) void k_proj(
    const __bf16* __restrict__ wqk, const __bf16* __restrict__ wv,
    const __bf16* __restrict__ y, __bf16* __restrict__ qout,
    __bf16* __restrict__ kout, __bf16* __restrict__ vout) {
  const int b = blockIdx.z;
  const int wave = threadIdx.x >> 6, lane = threadIdx.x & 63;
  const int l15 = lane & 15, quad = lane >> 4;
  const int obase = blockIdx.x * 64 + (wave >> 1) * 32;
  const int sbase = blockIdx.y * 64 + (wave & 1) * 32;
  const __bf16* Amat = (obase < 1024) ? (wqk + (size_t)obase * 512)
                                      : (wv + (size_t)(obase - 1024) * 512);
  const __bf16* Bbase = y + (size_t)b * 1024 * 512;

  const f32x4 fz = {0.f, 0.f, 0.f, 0.f};
  f32x4 acc[2][2];
#pragma unroll
  for (int io = 0; io < 2; ++io)
#pragma unroll
    for (int jo = 0; jo < 2; ++jo) acc[io][jo] = fz;

  for (int k0 = 0; k0 < 512; k0 += 32) {
    v8bf a0 = load8(Amat + (size_t)l15 * 512 + k0 + quad * 8);
    v8bf a1 = load8(Amat + (size_t)(16 + l15) * 512 + k0 + quad * 8);
    v8bf b0 = load8(Bbase + (size_t)(sbase + l15) * 512 + k0 + quad * 8);
    v8bf b1 = load8(Bbase + (size_t)(sbase + 16 + l15) * 512 + k0 + quad * 8);
    acc[0][0] = mfma16(a0, b0, acc[0][0]);
    acc[0][1] = mfma16(a0, b1, acc[0][1]);
    acc[1][0] = mfma16(a1, b0, acc[1][0]);
    acc[1][1] = mfma16(a1, b1, acc[1][1]);
  }

#pragma unroll
  for (int io = 0; io < 2; ++io)
#pragma unroll
    for (int jo = 0; jo < 2; ++jo)
#pragma unroll
      for (int r = 0; r < 4; ++r) {
        int o = obase + io * 16 + quad * 4 + r;   // C row = quad*4+reg
        int s = sbase + jo * 16 + l15;            // C col = lane&15
        float val = acc[io][jo][r];
        if (o < 512) {
          int n = o >> 7, d = o & 127;
          qout[(((size_t)b * 4 + n) * 1024 + s) * 128 + d] = (__bf16)(val * SCALE_Q);
        } else if (o < 1024) {
          int oe = o - 512; int n = oe >> 7, d = oe & 127;
          kout[(((size_t)b * 4 + n) * 1024 + s) * 128 + d] = (__bf16)val;
        } else {
          int oe = o - 1024; int n = oe >> 7, d = oe & 127;
          vout[(((size_t)b * 4 + n) * 128 + d) * 1024 + s] = (__bf16)val;
        }
      }
}

// ------------------------------------------------------------------
// Attention (unchanged).
// ------------------------------------------------------------------
__global__ __launch_bounds__(256) void k_attn(
    const __bf16* __restrict__ q, const __bf16* __restrict__ kmat,
    const __bf16* __restrict__ vt, const __bf16* __restrict__ relh,
    const __bf16* __restrict__ relw, const float* __restrict__ x,
    float* __restrict__ x2) {
  __shared__ __bf16 qld[16][136];
  __shared__ float rw[16][64];
  __shared__ float rh[16][64];
  __shared__ float pmax[4][16];
  __shared__ float psum[4][16];
  __shared__ __bf16 pld[16][1032];

  const int s0 = blockIdx.x * 16;
  const int n = blockIdx.y, b = blockIdx.z;
  const int tid = threadIdx.x;
  const int wave = tid >> 6, lane = tid & 63;
  const int l15 = lane & 15, quad = lane >> 4;
  const size_t hoff = ((size_t)(b * 4 + n)) << 17;

  {
    int flat = tid * 8, i = flat >> 7, d = flat & 127;
    *reinterpret_cast<v8bf*>(&qld[i][d]) = load8(q + hoff + (size_t)(s0 + i) * 128 + d);
  }
  __syncthreads();

  v8bf afrag[4];
#pragma unroll
  for (int kk = 0; kk < 4; ++kk)
    afrag[kk] = *reinterpret_cast<const v8bf*>(&qld[l15][kk * 32 + quad * 8]);

#pragma unroll
  for (int tb = 0; tb < 2; ++tb) {
    const __bf16* rel = tb ? relh : relw;
    float* dst = tb ? &rh[0][0] : &rw[0][0];
    int rr = wave * 16 + l15;
    bool ok = rr < 63;
    const __bf16* bp = rel + (size_t)(ok ? rr : 62) * 128;
    f32x4 acc = {0.f, 0.f, 0.f, 0.f};
#pragma unroll
    for (int kk = 0; kk < 4; ++kk) {
      v8bf bf = load8(bp + kk * 32 + quad * 8);
      if (!ok) bf = zero8();
      acc = mfma16(afrag[kk], bf, acc);
    }
#pragma unroll
    for (int r = 0; r < 4; ++r) dst[(quad * 4 + r) * 64 + wave * 16 + l15] = acc[r];
  }

  f32x4 sc[16];
#pragma unroll
  for (int jt = 0; jt < 16; ++jt) {
    int jb = wave * 256 + jt * 16;
    const __bf16* bp = kmat + hoff + (size_t)(jb + l15) * 128;
    f32x4 acc = {0.f, 0.f, 0.f, 0.f};
#pragma unroll
    for (int kk = 0; kk < 4; ++kk)
      acc = mfma16(afrag[kk], load8(bp + kk * 32 + quad * 8), acc);
    sc[jt] = acc;
  }
  __syncthreads();

  float rmax[4] = {-1e30f, -1e30f, -1e30f, -1e30f};
#pragma unroll
  for (int jt = 0; jt < 16; ++jt) {
    int j = wave * 256 + jt * 16 + l15;
    int hj = j >> 5, wj = j & 31;
#pragma unroll
    for (int r = 0; r < 4; ++r) {
      int i = quad * 4 + r;
      int si = s0 + i;
      float val = sc[jt][r] + rw[i][wj - (si & 31) + 31] + rh[i][hj - (si >> 5) + 31];
      sc[jt][r] = val;
      rmax[r] = fmaxf(rmax[r], val);
    }
  }
#pragma unroll
  for (int r = 0; r < 4; ++r)
#pragma unroll
    for (int msk = 8; msk >= 1; msk >>= 1)
      rmax[r] = fmaxf(rmax[r], __shfl_xor(rmax[r], msk));
  if (l15 == 0) {
#pragma unroll
    for (int r = 0; r < 4; ++r) pmax[wave][quad * 4 + r] = rmax[r];
  }
  __syncthreads();

  float M[4], rsum[4] = {0.f, 0.f, 0.f, 0.f};
#pragma unroll
  for (int r = 0; r < 4; ++r) {
    int i = quad * 4 + r;
    M[r] = fmaxf(fmaxf(pmax[0][i], pmax[1][i]), fmaxf(pmax[2][i], pmax[3][i]));
  }
#pragma unroll
  for (int jt = 0; jt < 16; ++jt) {
    int j = wave * 256 + jt * 16 + l15;
#pragma unroll
    for (int r = 0; r < 4; ++r) {
      float p = __expf(sc[jt][r] - M[r]);
      rsum[r] += p;
      pld[quad * 4 + r][j] = (__bf16)p;
    }
  }
#pragma unroll
  for (int r = 0; r < 4; ++r)
#pragma unroll
    for (int msk = 8; msk >= 1; msk >>= 1)
      rsum[r] += __shfl_xor(rsum[r], msk);
  if (l15 == 0) {
#pragma unroll
    for (int r = 0; r < 4; ++r) psum[wave][quad * 4 + r] = rsum[r];
  }
  __syncthreads();

  const f32x4 fz = {0.f, 0.f, 0.f, 0.f};
  f32x4 o0 = fz, o1 = fz;
  const int d0 = wave * 16, d1 = wave * 16 + 64;
  const __bf16* vb0 = vt + hoff + (size_t)(d0 + l15) * 1024;
  const __bf16* vb1 = vt + hoff + (size_t)(d1 + l15) * 1024;
  for (int j0 = 0; j0 < 1024; j0 += 32) {
    v8bf pa = *reinterpret_cast<const v8bf*>(&pld[l15][j0 + quad * 8]);
    o0 = mfma16(pa, load8(vb0 + j0 + quad * 8), o0);
    o1 = mfma16(pa, load8(vb1 + j0 + quad * 8), o1);
  }
#pragma unroll
  for (int r = 0; r < 4; ++r) {
    int i = quad * 4 + r;
    float inv = 1.0f / (psum[0][i] + psum[1][i] + psum[2][i] + psum[3][i]);
    int s = s0 + i;
    size_t i0 = ((size_t)b * 512 + n * 128 + d0 + l15) * 1024 + s;
    size_t i1 = ((size_t)b * 512 + n * 128 + d1 + l15) * 1024 + s;
    x2[i0] = o0[r] * inv + x[i0];
    x2[i1] = o1[r] * inv + x[i1];
  }
}

// ------------------------------------------------------------------
// 3x3 conv, m97 structure: 128x128 tile, BK=32, global_load_lds width 16.
// A = Wt[tap] (o,c k-contig); B = zero-padded z (b,34,34,c). K = 9*512.
// 4 waves, each 4x4 16x16 frags. out = conv + bias + x2 (fp32).
// ------------------------------------------------------------------
__global__ __launch_bounds__(256) void k_conv(
    const __bf16* __restrict__ Wt, const __bf16* __restrict__ zp,
    const float* __restrict__ bias, const float* __restrict__ x2,
    float* __restrict__ out) {
  __shared__ __bf16 As[128 * 32];
  __shared__ __bf16 Bs[128 * 32];
  const int t = threadIdx.x;
  const int wave = t >> 6, lane = t & 63;
  const int l15 = lane & 15, quad = lane >> 4;
  const int mbase = blockIdx.x * 128;   // o
  const int nbase = blockIdx.y * 128;   // (b,s) flat
  const int mh = (wave >> 1) * 64, nh = (wave & 1) * 64;

  // staging: chunk j = c*256 + t covers 16B: row=j>>2, k-part=(j&3)*8
  const int row0 = t >> 2;              // [0,64)
  const int part8 = (t & 3) * 8;
  const __bf16* gA0 = Wt + (size_t)(mbase + row0) * 512 + part8;
  const __bf16* gA1 = gA0 + (size_t)64 * 512;
  const int n0 = nbase + row0;
  const int b0 = n0 >> 10, sp = n0 & 1023;
  const __bf16* gB0 =
      zp + ((size_t)(b0 * 34 + (sp >> 5) + 1) * 34 + (sp & 31) + 1) * 512 + part8;
  const __bf16* gB1 = gB0 + (size_t)2 * 34 * 512;   // col+64 -> h+2
  __bf16* lA0 = As + (size_t)(wave * 64) * 8;
  __bf16* lA1 = As + (size_t)(256 + wave * 64) * 8;
  __bf16* lB0 = Bs + (size_t)(wave * 64) * 8;
  __bf16* lB1 = Bs + (size_t)(256 + wave * 64) * 8;

  const f32x4 fz = {0.f, 0.f, 0.f, 0.f};
  f32x4 acc[4][4];
#pragma unroll
  for (int i = 0; i < 4; ++i)
#pragma unroll
    for (int j = 0; j < 4; ++j) acc[i][j] = fz;

  for (int tap = 0; tap < 9; ++tap) {
    const int dh = tap / 3 - 1, dw = tap % 3 - 1;
    const size_t aoff = (size_t)tap * 512 * 512;
    const int boff = (dh * 34 + dw) * 512;
    for (int k0 = 0; k0 < 512; k0 += 32) {
      __syncthreads();  // previous compute done before overwrite
      gld16(gA0 + aoff + k0, lA0);
      gld16(gA1 + aoff + k0, lA1);
      gld16(gB0 + boff + k0, lB0);
      gld16(gB1 + boff + k0, lB1);
      __syncthreads();  // drains vmcnt -> tiles visible
      v8bf a[4], b[4];
#pragma unroll
      for (int i = 0; i < 4; ++i)
        a[i] = load8(&As[(size_t)(mh + i * 16 + l15) * 32 + quad * 8]);
#pragma unroll
      for (int j = 0; j < 4; ++j)
        b[j] = load8(&Bs[(size_t)(nh + j * 16 + l15) * 32 + quad * 8]);
#pragma unroll
      for (int i = 0; i < 4; ++i)
#pragma unroll
        for (int j = 0; j < 4; ++j) acc[i][j] = mfma16(a[i], b[j], acc[i][j]);
    }
  }

#pragma unroll
  for (int i = 0; i < 4; ++i)
#pragma unroll
    for (int j = 0; j < 4; ++j)
#pragma unroll
      for (int r = 0; r < 4; ++r) {
        int o = mbase + mh + i * 16 + quad * 4 + r;
        int n = nbase + nh + j * 16 + l15;
        int bb2 = n >> 10, s = n & 1023;
        size_t idx = ((size_t)bb2 * 512 + o) * 1024 + s;
        out[idx] = acc[i][j][r] + bias[o] + x2[idx];
      }
}

// ------------------------------------------------------------------
extern "C" void kernel_launch(void* const* d_in, const int* in_sizes, int n_in,
                              void* d_out, int out_size, void* d_ws, size_t ws_size,
                              hipStream_t stream) {
  const float* x    = (const float*)d_in[0];
  const float* wqk  = (const float*)d_in[1];
  const float* wv   = (const float*)d_in[2];
  const float* relh = (const float*)d_in[3];
  const float* relw = (const float*)d_in[4];
  const float* g1   = (const float*)d_in[5];
  const float* b1   = (const float*)d_in[6];
  const float* m1   = (const float*)d_in[7];
  const float* v1   = (const float*)d_in[8];
  const float* g2   = (const float*)d_in[9];
  const float* b2   = (const float*)d_in[10];
  const float* m2   = (const float*)d_in[11];
  const float* v2   = (const float*)d_in[12];
  const float* wfc  = (const float*)d_in[13];
  const float* bfc  = (const float*)d_in[14];
  float* out = (float*)d_out;

  char* p = (char*)d_ws;
  __bf16* y    = (__bf16*)p; p += (size_t)8 * 1024 * 512 * 2;       // (b,s,c)
  __bf16* qb   = (__bf16*)p; p += (size_t)8 * 4 * 1024 * 128 * 2;   // (b,n,s,d)
  __bf16* kb   = (__bf16*)p; p += (size_t)8 * 4 * 1024 * 128 * 2;   // (b,n,s,d)
  __bf16* vb   = (__bf16*)p; p += (size_t)8 * 4 * 1024 * 128 * 2;   // (b,n,d,s)
  __bf16* Wt   = (__bf16*)p; p += (size_t)9 * 512 * 512 * 2;        // (tap,o,c)
  __bf16* wqkb = (__bf16*)p; p += (size_t)1024 * 512 * 2;
  __bf16* wvb  = (__bf16*)p; p += (size_t)512 * 512 * 2;
  __bf16* rhb  = (__bf16*)p; p += 32768;
  __bf16* rwb  = (__bf16*)p; p += 32768;
  float*  x2   = (float*)p;  p += (size_t)8 * 512 * 1024 * 4;       // (b,c,s) fp32
  __bf16* zpad = (__bf16*)p; p += (size_t)8 * 34 * 34 * 512 * 2;    // padded z

  k_cast<<<dim3((1024 * 512 + 255) / 256), dim3(256), 0, stream>>>(wqk, wqkb, 1024 * 512);
  k_cast<<<dim3((512 * 512 + 255) / 256), dim3(256), 0, stream>>>(wv, wvb, 512 * 512);
  k_cast<<<dim3((63 * 128 + 255) / 256), dim3(256), 0, stream>>>(relh, rhb, 63 * 128);
  k_cast<<<dim3((63 * 128 + 255) / 256), dim3(256), 0, stream>>>(relw, rwb, 63 * 128);
  k_repack<<<dim3(9 * 512 * 512 / 256), dim3(256), 0, stream>>>(wfc, Wt);
  // zero padded z: 8*34*34*512 bf16 = 9469952 B = 591872 x 16B
  k_zero<<<dim3(591872 / 256), dim3(256), 0, stream>>>((float*)zpad);
  k_bn1<<<dim3(32, 16, 8), dim3(32, 8), 0, stream>>>(x, g1, b1, m1, v1, y);
  k_proj<<<dim3(24, 16, 8), dim3(256), 0, stream>>>(wqkb, wvb, y, qb, kb, vb);
  k_attn<<<dim3(64, 4, 8), dim3(256), 0, stream>>>(qb, kb, vb, rhb, rwb, x, x2);
  k_bn2<<<dim3(32, 16, 8), dim3(32, 8), 0, stream>>>(x2, g2, b2, m2, v2, zpad);
  k_conv<<<dim3(4, 64, 1), dim3(256), 0, stream>>>(Wt, zpad, bfc, x2, out);
}